// Round 12
// baseline (66.985 us; speedup 1.0000x reference)
//
#include <hip/hip_runtime.h>

#define B_SZ  16384
#define F_SZ  20
#define V_SZ  100000
#define E_SZ  32
#define DBOT  640
#define D1    512
#define D2    256
#define T1D   128
#define T2D   64
#define NDOM  4

typedef __bf16 bf16x8 __attribute__((ext_vector_type(8)));
typedef float  f32x4  __attribute__((ext_vector_type(4)));

#define MFMA(a, b, c) __builtin_amdgcn_mfma_f32_16x16x32_bf16((a), (b), (c), 0, 0, 0)

// ---------------------------------------------------------------------------
// Prep: pack all weights into MFMA-fragment order bf16 (unchanged).
// ---------------------------------------------------------------------------
__global__ __launch_bounds__(256) void k_prep(const float* __restrict__ W1,
                                              const float* __restrict__ W2,
                                              const float* __restrict__ TW1,
                                              const float* __restrict__ TW2,
                                              __bf16* __restrict__ W1P,
                                              __bf16* __restrict__ W2P,
                                              __bf16* __restrict__ TW1P,
                                              __bf16* __restrict__ TW2P) {
  int bid = blockIdx.x, tid = threadIdx.x;
  const float* src; __bf16* dst; int n, k, N;
  if (bid < 160) {
    long g = (long)bid * 256 + tid;
    int lane = g & 63; int kkg = (int)((g >> 6) % 20); int ntile = (int)(g / 1280);
    n = ntile * 16 + (lane & 15); k = kkg * 32 + ((lane >> 4) << 3);
    src = W1; N = D1; dst = W1P + g * 8;
  } else if (bid < 224) {
    long g = (long)(bid - 160) * 256 + tid;
    int lane = g & 63; int kkg = (int)((g >> 6) & 15); int ntile = (int)(g >> 10);
    n = ntile * 16 + (lane & 15); k = kkg * 32 + ((lane >> 4) << 3);
    src = W2; N = D2; dst = W2P + g * 8;
  } else if (bid < 288) {
    long g = (long)(bid - 224) * 256 + tid;
    int d = (int)(g >> 12); long r = g & 4095;
    int lane = r & 63; int kkg = (int)((r >> 6) & 7); int ntile = (int)(r >> 9);
    n = ntile * 16 + (lane & 15); k = kkg * 32 + ((lane >> 4) << 3);
    src = TW1 + (long)d * D2 * T1D; N = T1D;
    dst = TW1P + ((long)(d * 64 + ntile * 8 + kkg) * 64 + lane) * 8;
  } else {
    long g = (long)(bid - 288) * 256 + tid;
    int d = (int)(g >> 10); long r = g & 1023;
    int lane = r & 63; int kkg = (int)((r >> 6) & 3); int ntile = (int)(r >> 8);
    n = ntile * 16 + (lane & 15); k = kkg * 32 + ((lane >> 4) << 3);
    src = TW2 + (long)d * T1D * T2D; N = T2D;
    dst = TW2P + ((long)(d * 16 + ntile * 4 + kkg) * 64 + lane) * 8;
  }
  bf16x8 o;
#pragma unroll
  for (int e = 0; e < 8; ++e) o[e] = (__bf16)src[(long)(k + e) * N + n];
  *(bf16x8*)dst = o;
}

// ---------------------------------------------------------------------------
// MEGAFUSED + in-block domain bucketing.  R12 change vs R11: rows are
// bucketed by domain in LDS (concurrent with GEMM1); tower computes each
// row's OWN domain only (MFMA 4x -> ~1.2x, per-block TW L2 stream
// ~1.28MB -> ~0.4MB).  Wave w -> domain w>>1, half w&1; wave pair sweeps
// bucket d in 32-row chunks (loop covers rare >32 buckets).
// ---------------------------------------------------------------------------
__global__ __launch_bounds__(512) void k_mega(const int* __restrict__ fids,
                                              const int* __restrict__ dom,
                                              const float* __restrict__ emb,
                                              const __bf16* __restrict__ W1P,
                                              const float* __restrict__ b1,
                                              const __bf16* __restrict__ W2P,
                                              const float* __restrict__ b2,
                                              const __bf16* __restrict__ TW1P,
                                              const __bf16* __restrict__ TW2P,
                                              const float* __restrict__ Tb1,
                                              const float* __restrict__ Tb2,
                                              const float* __restrict__ TW3,
                                              const float* __restrict__ Tb3,
                                              float* __restrict__ out) {
  __shared__ __attribute__((aligned(16))) char smem[153664];
  int*    ids_lds = (int*)(smem + 147456);        // 5120B
  int*    bcnt    = (int*)(smem + 152576);        // 16B
  int*    blist   = (int*)(smem + 152592);        // 4*64*4 = 1024B
  __bf16* sA      = (__bf16*)smem;                // 81920B (rows 1280B, swz)
  __bf16* h1      = (__bf16*)(smem + 81920);      // 65536B (rows 1024B, swz)
  __bf16* h2_lds  = (__bf16*)smem;                // 32768B (rows 512B, swz)
  __bf16* t_lds   = (__bf16*)(smem + 32768);      // 32768B (8 waves x 4KB)

  int bid = blockIdx.x, tid = threadIdx.x;
  int lane = tid & 63, w = tid >> 6;
  int lrow = lane & 15, kq = lane >> 4;
  int m0 = bid * 64;

  // ---- stage feature ids; zero domain-bucket counters ----
  for (int i = tid; i < 64 * F_SZ; i += 512) ids_lds[i] = fids[m0 * F_SZ + i];
  if (tid < NDOM) bcnt[tid] = 0;
  __syncthreads();

  // ---- single-shot gather: 5120 (row, 8-elem) chunks / 512 thr = 10 each ----
  {
    float4 ga[10], gb[10];
    int sb[10];
#pragma unroll
    for (int i = 0; i < 10; ++i) {
      unsigned c = tid + i * 512;
      unsigned row = c / 80;
      unsigned cc = c - row * 80;
      int f = cc >> 2, es = (cc & 3) << 3;
      int id = ids_lds[row * F_SZ + f];
      const float* p = emb + ((long)f * V_SZ + id) * E_SZ + es;
      ga[i] = *(const float4*)p;
      gb[i] = *(const float4*)(p + 4);
      sb[i] = (int)(row * 1280 + cc * 16) ^ ((row & 7) << 4);
    }
#pragma unroll
    for (int i = 0; i < 10; ++i) {
      bf16x8 o;
      o[0] = (__bf16)ga[i].x; o[1] = (__bf16)ga[i].y;
      o[2] = (__bf16)ga[i].z; o[3] = (__bf16)ga[i].w;
      o[4] = (__bf16)gb[i].x; o[5] = (__bf16)gb[i].y;
      o[6] = (__bf16)gb[i].z; o[7] = (__bf16)gb[i].w;
      *(bf16x8*)((char*)sA + sb[i]) = o;
    }
  }
  __syncthreads();

  // ---- domain bucketing (concurrent with GEMM1; read before tower) ----
  if (tid < 64) {
    int d = dom[m0 + tid];
    int s = atomicAdd(&bcnt[d], 1);
    blist[d * 64 + s] = tid;
  }

  // ---- GEMM1 (barrier-free): h1[64x512] = relu(A @ W1 + b1) ----
  {
    f32x4 acc[4][4] = {};
#pragma unroll
    for (int f = 0; f < F_SZ; ++f) {
      bf16x8 af[4];
#pragma unroll
      for (int mi = 0; mi < 4; ++mi) {
        int byte = ((mi * 16 + lrow) * 1280 + (f * 32 + kq * 8) * 2) ^ ((lrow & 7) << 4);
        af[mi] = *(const bf16x8*)((const char*)sA + byte);
      }
#pragma unroll
      for (int ni = 0; ni < 4; ++ni) {
        bf16x8 bfr = *(const bf16x8*)(W1P +
            ((long)((w * 4 + ni) * 20 + f) * 64 + lane) * 8);
#pragma unroll
        for (int mi = 0; mi < 4; ++mi)
          acc[mi][ni] = MFMA(af[mi], bfr, acc[mi][ni]);
      }
    }
#pragma unroll
    for (int ni = 0; ni < 4; ++ni) {
      int col = w * 64 + ni * 16 + lrow;
      float bv = b1[col];
#pragma unroll
      for (int mi = 0; mi < 4; ++mi) {
#pragma unroll
        for (int r = 0; r < 4; ++r) {
          int row = mi * 16 + kq * 4 + r;
          float v = acc[mi][ni][r] + bv;
          v = v > 0.f ? v : 0.f;
          int byte = (row * 1024 + col * 2) ^ ((row & 7) << 4);
          *(__bf16*)((char*)h1 + byte) = (__bf16)v;
        }
      }
    }
  }
  __syncthreads();   // h1 complete; sA region dead -> reusable

  // ---- GEMM2 (barrier-free): h2[64x256] = relu(h1 @ W2 + b2) -> LDS ----
  {
    f32x4 acc2[4][2] = {};
#pragma unroll 4
    for (int kkg = 0; kkg < 16; ++kkg) {
      bf16x8 a2[4];
#pragma unroll
      for (int mi = 0; mi < 4; ++mi) {
        int byte = ((mi * 16 + lrow) * 1024 + kkg * 64 + kq * 16) ^ ((lrow & 7) << 4);
        a2[mi] = *(const bf16x8*)((const char*)h1 + byte);
      }
#pragma unroll
      for (int ni = 0; ni < 2; ++ni) {
        bf16x8 bfr = *(const bf16x8*)(W2P +
            ((long)((w * 2 + ni) * 16 + kkg) * 64 + lane) * 8);
#pragma unroll
        for (int mi = 0; mi < 4; ++mi)
          acc2[mi][ni] = MFMA(a2[mi], bfr, acc2[mi][ni]);
      }
    }
    // h2 -> LDS (rows 512B, swizzled by row&7)
#pragma unroll
    for (int ni = 0; ni < 2; ++ni) {
      int col = w * 32 + ni * 16 + lrow;
      float bv = b2[col];
#pragma unroll
      for (int mi = 0; mi < 4; ++mi) {
#pragma unroll
        for (int r = 0; r < 4; ++r) {
          int row = mi * 16 + kq * 4 + r;
          float v = acc2[mi][ni][r] + bv;
          v = v > 0.f ? v : 0.f;
          int byte = (row * 512 + col * 2) ^ ((row & 7) << 4);
          *(__bf16*)((char*)h2_lds + byte) = (__bf16)v;
        }
      }
    }
  }
  __syncthreads();   // h2 + buckets complete

  // ---- Tower (bucketed): wave w -> domain w>>1, half w&1 ----
  {
    int d = w >> 1;
    int nc = bcnt[d];
    __bf16* tw = t_lds + w * 2048;        // per-wave 16x128 scratch

    for (int base = (w & 1) * 16; base < nc; base += 32) {
      int slot = base + lrow;
      bool valid = slot < nc;
      int grow = blist[d * 64 + (valid ? slot : 0)];

      // a1 fragments from h2_lds (per-lane row indirection)
      bf16x8 a1[8];
#pragma unroll
      for (int kk = 0; kk < 8; ++kk) {
        int byte = (grow * 512 + (kk * 32 + kq * 8) * 2) ^ ((grow & 7) << 4);
        a1[kk] = *(const bf16x8*)((const char*)h2_lds + byte);
      }

      // t1 = relu(h2 @ TW1[d] + Tb1[d])  (16 x 128)
      f32x4 acc1[8] = {};
#pragma unroll
      for (int kk = 0; kk < 8; ++kk) {
#pragma unroll
        for (int ni = 0; ni < 8; ++ni) {
          bf16x8 b = *(const bf16x8*)(TW1P +
              ((long)(d * 64 + ni * 8 + kk) * 64 + lane) * 8);
          acc1[ni] = MFMA(a1[kk], b, acc1[ni]);
        }
      }
#pragma unroll
      for (int ni = 0; ni < 8; ++ni) {
        float bv = Tb1[d * T1D + ni * 16 + lrow];
#pragma unroll
        for (int r = 0; r < 4; ++r) {
          float v = acc1[ni][r] + bv;
          v = v > 0.f ? v : 0.f;
          tw[(kq * 4 + r) * 128 + ni * 16 + lrow] = (__bf16)v;
        }
      }
      asm volatile("s_waitcnt lgkmcnt(0)" ::: "memory");

      // t2 = relu(t1 @ TW2[d] + Tb2[d])  (16 x 64)
      bf16x8 a2f[4];
#pragma unroll
      for (int kk = 0; kk < 4; ++kk)
        a2f[kk] = *(const bf16x8*)(&tw[lrow * 128 + kk * 32 + kq * 8]);
      f32x4 acc2[4] = {};
#pragma unroll
      for (int kk = 0; kk < 4; ++kk) {
#pragma unroll
        for (int ni = 0; ni < 4; ++ni) {
          bf16x8 b = *(const bf16x8*)(TW2P +
              ((long)(d * 16 + ni * 4 + kk) * 64 + lane) * 8);
          acc2[ni] = MFMA(a2f[kk], b, acc2[ni]);
        }
      }
      asm volatile("s_waitcnt lgkmcnt(0)" ::: "memory");
#pragma unroll
      for (int ni = 0; ni < 4; ++ni) {
        float bv = Tb2[d * T2D + ni * 16 + lrow];
#pragma unroll
        for (int r = 0; r < 4; ++r) {
          float v = acc2[ni][r] + bv;
          v = v > 0.f ? v : 0.f;
          tw[(kq * 4 + r) * 64 + ni * 16 + lrow] = (__bf16)v;
        }
      }
      asm volatile("s_waitcnt lgkmcnt(0)" ::: "memory");

      // logit + sigmoid + store (domain == row's own by construction)
      float s = 0.f;
#pragma unroll
      for (int j = 0; j < 16; ++j)
        s += (float)tw[lrow * 64 + kq * 16 + j] * TW3[d * T2D + kq * 16 + j];
      s += __shfl_xor(s, 16);
      s += __shfl_xor(s, 32);
      s += Tb3[d];
      if (kq == 0 && valid)
        out[m0 + grow] = 1.0f / (1.0f + expf(-s));
      asm volatile("s_waitcnt lgkmcnt(0)" ::: "memory");  // tw reuse next iter
    }
  }
}

// ---------------------------------------------------------------------------
extern "C" void kernel_launch(void* const* d_in, const int* in_sizes, int n_in,
                              void* d_out, int out_size, void* d_ws, size_t ws_size,
                              hipStream_t stream) {
  const int*   fids = (const int*)d_in[0];
  const int*   dom  = (const int*)d_in[1];
  const float* emb  = (const float*)d_in[2];
  const float* W1   = (const float*)d_in[3];
  const float* b1   = (const float*)d_in[4];
  const float* W2   = (const float*)d_in[5];
  const float* b2   = (const float*)d_in[6];
  const float* TW1  = (const float*)d_in[7];
  const float* Tb1  = (const float*)d_in[8];
  const float* TW2  = (const float*)d_in[9];
  const float* Tb2  = (const float*)d_in[10];
  const float* TW3  = (const float*)d_in[11];
  const float* Tb3  = (const float*)d_in[12];
  float* out = (float*)d_out;

  char* ws = (char*)d_ws;
  __bf16* W1P   = (__bf16*)(ws);                 // 655360
  __bf16* W2P   = (__bf16*)(ws + 655360);        // 262144
  __bf16* TW1P  = (__bf16*)(ws + 917504);        // 262144
  __bf16* TW2P  = (__bf16*)(ws + 1179648);       // 65536

  k_prep<<<304, 256, 0, stream>>>(W1, W2, TW1, TW2, W1P, W2P, TW1P, TW2P);
  k_mega<<<256, 512, 0, stream>>>(fids, dom, emb, W1P, b1, W2P, b2,
                                  TW1P, TW2P, Tb1, Tb2, TW3, Tb3, out);
}

// Round 13
// 47.100 us; speedup vs baseline: 1.4222x; 1.4222x over previous
//
#include <hip/hip_runtime.h>

#define B_SZ  16384
#define F_SZ  20
#define V_SZ  100000
#define E_SZ  32
#define DBOT  640
#define D1    512
#define D2    256
#define T1D   128
#define T2D   64
#define NDOM  4

typedef __bf16 bf16x8 __attribute__((ext_vector_type(8)));
typedef float  f32x4  __attribute__((ext_vector_type(4)));

#define MFMA(a, b, c) __builtin_amdgcn_mfma_f32_16x16x32_bf16((a), (b), (c), 0, 0, 0)

// ---------------------------------------------------------------------------
// Prep: pack all weights into MFMA-fragment order bf16 (unchanged).
// ---------------------------------------------------------------------------
__global__ __launch_bounds__(256) void k_prep(const float* __restrict__ W1,
                                              const float* __restrict__ W2,
                                              const float* __restrict__ TW1,
                                              const float* __restrict__ TW2,
                                              __bf16* __restrict__ W1P,
                                              __bf16* __restrict__ W2P,
                                              __bf16* __restrict__ TW1P,
                                              __bf16* __restrict__ TW2P) {
  int bid = blockIdx.x, tid = threadIdx.x;
  const float* src; __bf16* dst; int n, k, N;
  if (bid < 160) {
    long g = (long)bid * 256 + tid;
    int lane = g & 63; int kkg = (int)((g >> 6) % 20); int ntile = (int)(g / 1280);
    n = ntile * 16 + (lane & 15); k = kkg * 32 + ((lane >> 4) << 3);
    src = W1; N = D1; dst = W1P + g * 8;
  } else if (bid < 224) {
    long g = (long)(bid - 160) * 256 + tid;
    int lane = g & 63; int kkg = (int)((g >> 6) & 15); int ntile = (int)(g >> 10);
    n = ntile * 16 + (lane & 15); k = kkg * 32 + ((lane >> 4) << 3);
    src = W2; N = D2; dst = W2P + g * 8;
  } else if (bid < 288) {
    long g = (long)(bid - 224) * 256 + tid;
    int d = (int)(g >> 12); long r = g & 4095;
    int lane = r & 63; int kkg = (int)((r >> 6) & 7); int ntile = (int)(r >> 9);
    n = ntile * 16 + (lane & 15); k = kkg * 32 + ((lane >> 4) << 3);
    src = TW1 + (long)d * D2 * T1D; N = T1D;
    dst = TW1P + ((long)(d * 64 + ntile * 8 + kkg) * 64 + lane) * 8;
  } else {
    long g = (long)(bid - 288) * 256 + tid;
    int d = (int)(g >> 10); long r = g & 1023;
    int lane = r & 63; int kkg = (int)((r >> 6) & 3); int ntile = (int)(r >> 8);
    n = ntile * 16 + (lane & 15); k = kkg * 32 + ((lane >> 4) << 3);
    src = TW2 + (long)d * T1D * T2D; N = T2D;
    dst = TW2P + ((long)(d * 16 + ntile * 4 + kkg) * 64 + lane) * 8;
  }
  bf16x8 o;
#pragma unroll
  for (int e = 0; e < 8; ++e) o[e] = (__bf16)src[(long)(k + e) * N + n];
  *(bf16x8*)dst = o;
}

// ---------------------------------------------------------------------------
// MEGAFUSED (R11 base).  R13 change: tower restructured -- wave w handles
// domain w>>1, rows (w&1)*32..+31 (ONE pass of 32 rows instead of TWO
// sequential 16-row domain passes): serial t1->t2->dot chain halved, tower
// weight stream per wave halved, t_lds moved to dead-h1 region and
// XOR-swizzled (R11 tower reads were 16-way bank conflicts).
// Every row stored exactly once: by its own domain's wave pair.
// ---------------------------------------------------------------------------
__global__ __launch_bounds__(512) void k_mega(const int* __restrict__ fids,
                                              const int* __restrict__ dom,
                                              const float* __restrict__ emb,
                                              const __bf16* __restrict__ W1P,
                                              const float* __restrict__ b1,
                                              const __bf16* __restrict__ W2P,
                                              const float* __restrict__ b2,
                                              const __bf16* __restrict__ TW1P,
                                              const __bf16* __restrict__ TW2P,
                                              const float* __restrict__ Tb1,
                                              const float* __restrict__ Tb2,
                                              const float* __restrict__ TW3,
                                              const float* __restrict__ Tb3,
                                              float* __restrict__ out) {
  __shared__ __attribute__((aligned(16))) char smem[152576];
  int*    ids_lds = (int*)(smem + 147456);        // 5120B (tail)
  __bf16* sA      = (__bf16*)smem;                // 81920B (rows 1280B, swz)
  __bf16* h1      = (__bf16*)(smem + 81920);      // 65536B (rows 1024B, swz)
  __bf16* h2_lds  = (__bf16*)smem;                // 32768B (rows 512B, swz)
  __bf16* t_lds   = (__bf16*)(smem + 81920);      // 64KB: 8 waves x 8KB (dead h1)

  int bid = blockIdx.x, tid = threadIdx.x;
  int lane = tid & 63, w = tid >> 6;
  int lrow = lane & 15, kq = lane >> 4;
  int m0 = bid * 64;

  // ---- stage feature ids ----
  for (int i = tid; i < 64 * F_SZ; i += 512) ids_lds[i] = fids[m0 * F_SZ + i];
  __syncthreads();

  // ---- single-shot gather: 5120 (row, 8-elem) chunks / 512 thr = 10 each ----
  {
    float4 ga[10], gb[10];
    int sb[10];
#pragma unroll
    for (int i = 0; i < 10; ++i) {
      unsigned c = tid + i * 512;
      unsigned row = c / 80;
      unsigned cc = c - row * 80;
      int f = cc >> 2, es = (cc & 3) << 3;
      int id = ids_lds[row * F_SZ + f];
      const float* p = emb + ((long)f * V_SZ + id) * E_SZ + es;
      ga[i] = *(const float4*)p;
      gb[i] = *(const float4*)(p + 4);
      sb[i] = (int)(row * 1280 + cc * 16) ^ ((row & 7) << 4);
    }
#pragma unroll
    for (int i = 0; i < 10; ++i) {
      bf16x8 o;
      o[0] = (__bf16)ga[i].x; o[1] = (__bf16)ga[i].y;
      o[2] = (__bf16)ga[i].z; o[3] = (__bf16)ga[i].w;
      o[4] = (__bf16)gb[i].x; o[5] = (__bf16)gb[i].y;
      o[6] = (__bf16)gb[i].z; o[7] = (__bf16)gb[i].w;
      *(bf16x8*)((char*)sA + sb[i]) = o;
    }
  }
  __syncthreads();

  // ---- GEMM1 (barrier-free): h1[64x512] = relu(A @ W1 + b1) ----
  {
    f32x4 acc[4][4] = {};
#pragma unroll
    for (int f = 0; f < F_SZ; ++f) {
      bf16x8 af[4];
#pragma unroll
      for (int mi = 0; mi < 4; ++mi) {
        int byte = ((mi * 16 + lrow) * 1280 + (f * 32 + kq * 8) * 2) ^ ((lrow & 7) << 4);
        af[mi] = *(const bf16x8*)((const char*)sA + byte);
      }
#pragma unroll
      for (int ni = 0; ni < 4; ++ni) {
        bf16x8 bfr = *(const bf16x8*)(W1P +
            ((long)((w * 4 + ni) * 20 + f) * 64 + lane) * 8);
#pragma unroll
        for (int mi = 0; mi < 4; ++mi)
          acc[mi][ni] = MFMA(af[mi], bfr, acc[mi][ni]);
      }
    }
#pragma unroll
    for (int ni = 0; ni < 4; ++ni) {
      int col = w * 64 + ni * 16 + lrow;
      float bv = b1[col];
#pragma unroll
      for (int mi = 0; mi < 4; ++mi) {
#pragma unroll
        for (int r = 0; r < 4; ++r) {
          int row = mi * 16 + kq * 4 + r;
          float v = acc[mi][ni][r] + bv;
          v = v > 0.f ? v : 0.f;
          int byte = (row * 1024 + col * 2) ^ ((row & 7) << 4);
          *(__bf16*)((char*)h1 + byte) = (__bf16)v;
        }
      }
    }
  }
  __syncthreads();   // h1 complete; sA region dead -> reusable (h2_lds)

  // ---- GEMM2 (barrier-free): h2[64x256] = relu(h1 @ W2 + b2) -> LDS ----
  {
    f32x4 acc2[4][2] = {};
#pragma unroll 4
    for (int kkg = 0; kkg < 16; ++kkg) {
      bf16x8 a2[4];
#pragma unroll
      for (int mi = 0; mi < 4; ++mi) {
        int byte = ((mi * 16 + lrow) * 1024 + kkg * 64 + kq * 16) ^ ((lrow & 7) << 4);
        a2[mi] = *(const bf16x8*)((const char*)h1 + byte);
      }
#pragma unroll
      for (int ni = 0; ni < 2; ++ni) {
        bf16x8 bfr = *(const bf16x8*)(W2P +
            ((long)((w * 2 + ni) * 16 + kkg) * 64 + lane) * 8);
#pragma unroll
        for (int mi = 0; mi < 4; ++mi)
          acc2[mi][ni] = MFMA(a2[mi], bfr, acc2[mi][ni]);
      }
    }
    // h2 -> LDS (rows 512B, swizzled by row&7)
#pragma unroll
    for (int ni = 0; ni < 2; ++ni) {
      int col = w * 32 + ni * 16 + lrow;
      float bv = b2[col];
#pragma unroll
      for (int mi = 0; mi < 4; ++mi) {
#pragma unroll
        for (int r = 0; r < 4; ++r) {
          int row = mi * 16 + kq * 4 + r;
          float v = acc2[mi][ni][r] + bv;
          v = v > 0.f ? v : 0.f;
          int byte = (row * 512 + col * 2) ^ ((row & 7) << 4);
          *(__bf16*)((char*)h2_lds + byte) = (__bf16)v;
        }
      }
    }
  }
  __syncthreads();   // h2 complete; h1 region dead -> t_lds

  // ---- Tower: wave w -> domain w>>1, rows (w&1)*32..+31, ONE pass ----
  {
    int d  = w >> 1;
    int r0 = (w & 1) * 32;
    __bf16* tw = t_lds + w * 4096;      // 8KB per wave (32 x 128 bf16)

    // a1 fragments from h2_lds: 2 row-tiles of 16
    bf16x8 a1[2][8];
#pragma unroll
    for (int mi = 0; mi < 2; ++mi)
#pragma unroll
      for (int kk = 0; kk < 8; ++kk) {
        int row = r0 + mi * 16 + lrow;
        int byte = (row * 512 + (kk * 32 + kq * 8) * 2) ^ ((row & 7) << 4);
        a1[mi][kk] = *(const bf16x8*)((const char*)h2_lds + byte);
      }

    // t1 = relu(h2 @ TW1[d] + Tb1[d])  (32 x 128)
    f32x4 acc1[2][8] = {};
#pragma unroll
    for (int kk = 0; kk < 8; ++kk) {
#pragma unroll
      for (int ni = 0; ni < 8; ++ni) {
        bf16x8 b = *(const bf16x8*)(TW1P +
            ((long)(d * 64 + ni * 8 + kk) * 64 + lane) * 8);
#pragma unroll
        for (int mi = 0; mi < 2; ++mi)
          acc1[mi][ni] = MFMA(a1[mi][kk], b, acc1[mi][ni]);
      }
    }
#pragma unroll
    for (int ni = 0; ni < 8; ++ni) {
      float bv = Tb1[d * T1D + ni * 16 + lrow];
#pragma unroll
      for (int mi = 0; mi < 2; ++mi) {
#pragma unroll
        for (int r = 0; r < 4; ++r) {
          int lr = mi * 16 + kq * 4 + r;
          float v = acc1[mi][ni][r] + bv;
          v = v > 0.f ? v : 0.f;
          int byte = (lr * 256 + (ni * 16 + lrow) * 2) ^ ((lr & 7) << 4);
          *(__bf16*)((char*)tw + byte) = (__bf16)v;
        }
      }
    }
    asm volatile("s_waitcnt lgkmcnt(0)" ::: "memory");

    // t2 = relu(t1 @ TW2[d] + Tb2[d])  (32 x 64)
    bf16x8 a2f[2][4];
#pragma unroll
    for (int mi = 0; mi < 2; ++mi)
#pragma unroll
      for (int kk = 0; kk < 4; ++kk) {
        int lr = mi * 16 + lrow;
        int byte = (lr * 256 + (kk * 32 + kq * 8) * 2) ^ ((lr & 7) << 4);
        a2f[mi][kk] = *(const bf16x8*)((const char*)tw + byte);
      }
    asm volatile("s_waitcnt lgkmcnt(0)" ::: "memory");  // reads done before overwrite
    f32x4 acc2[2][4] = {};
#pragma unroll
    for (int kk = 0; kk < 4; ++kk) {
#pragma unroll
      for (int ni = 0; ni < 4; ++ni) {
        bf16x8 b = *(const bf16x8*)(TW2P +
            ((long)(d * 16 + ni * 4 + kk) * 64 + lane) * 8);
#pragma unroll
        for (int mi = 0; mi < 2; ++mi)
          acc2[mi][ni] = MFMA(a2f[mi][kk], b, acc2[mi][ni]);
      }
    }
#pragma unroll
    for (int ni = 0; ni < 4; ++ni) {
      float bv = Tb2[d * T2D + ni * 16 + lrow];
#pragma unroll
      for (int mi = 0; mi < 2; ++mi) {
#pragma unroll
        for (int r = 0; r < 4; ++r) {
          int lr = mi * 16 + kq * 4 + r;
          float v = acc2[mi][ni][r] + bv;
          v = v > 0.f ? v : 0.f;
          int byte = (lr * 128 + (ni * 16 + lrow) * 2) ^ ((lr & 7) << 4);
          *(__bf16*)((char*)tw + byte) = (__bf16)v;
        }
      }
    }
    asm volatile("s_waitcnt lgkmcnt(0)" ::: "memory");

    // logit + sigmoid + select-store.  lane -> local row lr = (kq&1)*16+lrow,
    // k-half = kq>>1 (32 elems each); lane^32 is the same row's other half.
    {
      int lr    = (kq & 1) * 16 + lrow;
      int khalf = kq >> 1;
      float s = 0.f;
#pragma unroll
      for (int j = 0; j < 32; ++j) {
        int col = khalf * 32 + j;
        int byte = (lr * 128 + col * 2) ^ ((lr & 7) << 4);
        s += (float)*(const __bf16*)((const char*)tw + byte) * TW3[d * T2D + col];
      }
      s += __shfl_xor(s, 32);
      s += Tb3[d];
      int grow = r0 + lr;
      if (khalf == 0 && dom[m0 + grow] == d)
        out[m0 + grow] = 1.0f / (1.0f + expf(-s));
    }
  }
}

// ---------------------------------------------------------------------------
extern "C" void kernel_launch(void* const* d_in, const int* in_sizes, int n_in,
                              void* d_out, int out_size, void* d_ws, size_t ws_size,
                              hipStream_t stream) {
  const int*   fids = (const int*)d_in[0];
  const int*   dom  = (const int*)d_in[1];
  const float* emb  = (const float*)d_in[2];
  const float* W1   = (const float*)d_in[3];
  const float* b1   = (const float*)d_in[4];
  const float* W2   = (const float*)d_in[5];
  const float* b2   = (const float*)d_in[6];
  const float* TW1  = (const float*)d_in[7];
  const float* Tb1  = (const float*)d_in[8];
  const float* TW2  = (const float*)d_in[9];
  const float* Tb2  = (const float*)d_in[10];
  const float* TW3  = (const float*)d_in[11];
  const float* Tb3  = (const float*)d_in[12];
  float* out = (float*)d_out;

  char* ws = (char*)d_ws;
  __bf16* W1P   = (__bf16*)(ws);                 // 655360
  __bf16* W2P   = (__bf16*)(ws + 655360);        // 262144
  __bf16* TW1P  = (__bf16*)(ws + 917504);        // 262144
  __bf16* TW2P  = (__bf16*)(ws + 1179648);       // 65536

  k_prep<<<304, 256, 0, stream>>>(W1, W2, TW1, TW2, W1P, W2P, TW1P, TW2P);
  k_mega<<<256, 512, 0, stream>>>(fids, dom, emb, W1P, b1, W2P, b2,
                                  TW1P, TW2P, Tb1, Tb2, TW3, Tb3, out);
}

// Round 14
// 44.102 us; speedup vs baseline: 1.5188x; 1.0680x over previous
//
#include <hip/hip_runtime.h>

#define B_SZ  16384
#define F_SZ  20
#define V_SZ  100000
#define E_SZ  32
#define DBOT  640
#define D1    512
#define D2    256
#define T1D   128
#define T2D   64
#define NDOM  4

typedef __bf16 bf16x8 __attribute__((ext_vector_type(8)));
typedef float  f32x4  __attribute__((ext_vector_type(4)));

#define MFMA(a, b, c) __builtin_amdgcn_mfma_f32_16x16x32_bf16((a), (b), (c), 0, 0, 0)

// ---------------------------------------------------------------------------
// Prep: pack all weights into MFMA-fragment order bf16 (unchanged).
// ---------------------------------------------------------------------------
__global__ __launch_bounds__(256) void k_prep(const float* __restrict__ W1,
                                              const float* __restrict__ W2,
                                              const float* __restrict__ TW1,
                                              const float* __restrict__ TW2,
                                              __bf16* __restrict__ W1P,
                                              __bf16* __restrict__ W2P,
                                              __bf16* __restrict__ TW1P,
                                              __bf16* __restrict__ TW2P) {
  int bid = blockIdx.x, tid = threadIdx.x;
  const float* src; __bf16* dst; int n, k, N;
  if (bid < 160) {
    long g = (long)bid * 256 + tid;
    int lane = g & 63; int kkg = (int)((g >> 6) % 20); int ntile = (int)(g / 1280);
    n = ntile * 16 + (lane & 15); k = kkg * 32 + ((lane >> 4) << 3);
    src = W1; N = D1; dst = W1P + g * 8;
  } else if (bid < 224) {
    long g = (long)(bid - 160) * 256 + tid;
    int lane = g & 63; int kkg = (int)((g >> 6) & 15); int ntile = (int)(g >> 10);
    n = ntile * 16 + (lane & 15); k = kkg * 32 + ((lane >> 4) << 3);
    src = W2; N = D2; dst = W2P + g * 8;
  } else if (bid < 288) {
    long g = (long)(bid - 224) * 256 + tid;
    int d = (int)(g >> 12); long r = g & 4095;
    int lane = r & 63; int kkg = (int)((r >> 6) & 7); int ntile = (int)(r >> 9);
    n = ntile * 16 + (lane & 15); k = kkg * 32 + ((lane >> 4) << 3);
    src = TW1 + (long)d * D2 * T1D; N = T1D;
    dst = TW1P + ((long)(d * 64 + ntile * 8 + kkg) * 64 + lane) * 8;
  } else {
    long g = (long)(bid - 288) * 256 + tid;
    int d = (int)(g >> 10); long r = g & 1023;
    int lane = r & 63; int kkg = (int)((r >> 6) & 3); int ntile = (int)(r >> 8);
    n = ntile * 16 + (lane & 15); k = kkg * 32 + ((lane >> 4) << 3);
    src = TW2 + (long)d * T1D * T2D; N = T2D;
    dst = TW2P + ((long)(d * 16 + ntile * 4 + kkg) * 64 + lane) * 8;
  }
  bf16x8 o;
#pragma unroll
  for (int e = 0; e < 8; ++e) o[e] = (__bf16)src[(long)(k + e) * N + n];
  *(bf16x8*)dst = o;
}

// ---------------------------------------------------------------------------
// MEGAFUSED (R13 base).  R14 change: gather software-pipelined under GEMM1.
// 5 groups x 4 features.  Per group: commit regs->sA | lgkm-only barrier |
// prefetch B-frags(g) (OLDER vmem) | sched_barrier | issue gathers(g+1)
// (YOUNGEST vmem -> B-frag waits never drain them, R6 discipline) | 64 MFMA.
// Each group's gathers get a full phase (~2us >> 900cy HBM latency) in
// flight; per-phase gather BW (~8MB chip) ~= phase compute -> overlap.
// Exposed gather = 1-group pipeline fill instead of the whole 41MB.
// GEMM2 / tower / prep byte-identical to R13.
// ---------------------------------------------------------------------------
__global__ __launch_bounds__(512) void k_mega(const int* __restrict__ fids,
                                              const int* __restrict__ dom,
                                              const float* __restrict__ emb,
                                              const __bf16* __restrict__ W1P,
                                              const float* __restrict__ b1,
                                              const __bf16* __restrict__ W2P,
                                              const float* __restrict__ b2,
                                              const __bf16* __restrict__ TW1P,
                                              const __bf16* __restrict__ TW2P,
                                              const float* __restrict__ Tb1,
                                              const float* __restrict__ Tb2,
                                              const float* __restrict__ TW3,
                                              const float* __restrict__ Tb3,
                                              float* __restrict__ out) {
  __shared__ __attribute__((aligned(16))) char smem[152576];
  int*    ids_lds = (int*)(smem + 147456);        // 5120B (tail)
  __bf16* sA      = (__bf16*)smem;                // 81920B (rows 1280B, swz)
  __bf16* h1      = (__bf16*)(smem + 81920);      // 65536B (rows 1024B, swz)
  __bf16* h2_lds  = (__bf16*)smem;                // 32768B (rows 512B, swz)
  __bf16* t_lds   = (__bf16*)(smem + 81920);      // 64KB: 8 waves x 8KB

  int bid = blockIdx.x, tid = threadIdx.x;
  int lane = tid & 63, w = tid >> 6;
  int lrow = lane & 15, kq = lane >> 4;
  int m0 = bid * 64;

  // ---- stage feature ids ----
  for (int i = tid; i < 64 * F_SZ; i += 512) ids_lds[i] = fids[m0 * F_SZ + i];
  __syncthreads();

  // ---- pipelined gather + GEMM1 ----
  // chunk mapping per group g: 1024 chunks c = tid + i*512 (i=0,1);
  // row = c>>4, cc16 = c&15; feature f = g*4 + (cc16>>2), elems (cc16&3)*8.
  // sbyte(g) = [(row*1280 + cc16*16) ^ ((row&7)<<4)] + g*256  (XOR commutes:
  // g*256 touches only bits >=8, swizzle XOR touches bits 4-6).
  int row0 = tid >> 4,          cc0 = tid & 15;
  int row1 = (tid + 512) >> 4,  cc1 = tid & 15;   // i=1: rows 32-63
  int sb0 = (row0 * 1280 + cc0 * 16) ^ ((row0 & 7) << 4);
  int sb1 = (row1 * 1280 + cc1 * 16) ^ ((row1 & 7) << 4);
  int f0base = cc0 >> 2, es0 = (cc0 & 3) << 3;
  int f1base = cc1 >> 2, es1 = (cc1 & 3) << 3;

  float4 g0a, g0b, g1a, g1b;
  // prologue: issue gathers for group 0
  {
    int f = f0base;
    int id = ids_lds[row0 * F_SZ + f];
    const float* p = emb + ((long)f * V_SZ + id) * E_SZ + es0;
    g0a = *(const float4*)p; g0b = *(const float4*)(p + 4);
    f = f1base;
    id = ids_lds[row1 * F_SZ + f];
    const float* q = emb + ((long)f * V_SZ + id) * E_SZ + es1;
    g1a = *(const float4*)q; g1b = *(const float4*)(q + 4);
  }

  f32x4 acc[4][4] = {};

#pragma unroll
  for (int g = 0; g < 5; ++g) {
    // commit group g staged regs -> sA (register dep waits the gathers)
    {
      bf16x8 o;
      o[0] = (__bf16)g0a.x; o[1] = (__bf16)g0a.y; o[2] = (__bf16)g0a.z; o[3] = (__bf16)g0a.w;
      o[4] = (__bf16)g0b.x; o[5] = (__bf16)g0b.y; o[6] = (__bf16)g0b.z; o[7] = (__bf16)g0b.w;
      *(bf16x8*)((char*)sA + sb0 + g * 256) = o;
      o[0] = (__bf16)g1a.x; o[1] = (__bf16)g1a.y; o[2] = (__bf16)g1a.z; o[3] = (__bf16)g1a.w;
      o[4] = (__bf16)g1b.x; o[5] = (__bf16)g1b.y; o[6] = (__bf16)g1b.z; o[7] = (__bf16)g1b.w;
      *(bf16x8*)((char*)sA + sb1 + g * 256) = o;
    }
    asm volatile("s_waitcnt lgkmcnt(0)" ::: "memory");
    __builtin_amdgcn_s_barrier();
    __builtin_amdgcn_sched_barrier(0);

    // prefetch B-frags for group g (issued BEFORE next gathers -> older)
    bf16x8 bfr[4][4];
#pragma unroll
    for (int f4 = 0; f4 < 4; ++f4)
#pragma unroll
      for (int ni = 0; ni < 4; ++ni)
        bfr[f4][ni] = *(const bf16x8*)(W1P +
            ((long)((w * 4 + ni) * 20 + g * 4 + f4) * 64 + lane) * 8);
    __builtin_amdgcn_sched_barrier(0);

    // issue gathers for group g+1 (YOUNGEST vmem)
    if (g < 4) {
      int f = (g + 1) * 4 + f0base;
      int id = ids_lds[row0 * F_SZ + f];
      const float* p = emb + ((long)f * V_SZ + id) * E_SZ + es0;
      g0a = *(const float4*)p; g0b = *(const float4*)(p + 4);
      f = (g + 1) * 4 + f1base;
      id = ids_lds[row1 * F_SZ + f];
      const float* q = emb + ((long)f * V_SZ + id) * E_SZ + es1;
      g1a = *(const float4*)q; g1b = *(const float4*)(q + 4);
    }
    __builtin_amdgcn_sched_barrier(0);

    // MFMA group g (af from sA, B from prefetched regs)
#pragma unroll
    for (int f4 = 0; f4 < 4; ++f4) {
      int f = g * 4 + f4;
      bf16x8 af[4];
#pragma unroll
      for (int mi = 0; mi < 4; ++mi) {
        int byte = ((mi * 16 + lrow) * 1280 + (f * 32 + kq * 8) * 2) ^ ((lrow & 7) << 4);
        af[mi] = *(const bf16x8*)((const char*)sA + byte);
      }
#pragma unroll
      for (int ni = 0; ni < 4; ++ni)
#pragma unroll
        for (int mi = 0; mi < 4; ++mi)
          acc[mi][ni] = MFMA(af[mi], bfr[f4][ni], acc[mi][ni]);
    }
  }

  // ---- h1 = relu(. + b1) -> LDS (XOR-swizzled rows, 1024B stride) ----
#pragma unroll
  for (int ni = 0; ni < 4; ++ni) {
    int col = w * 64 + ni * 16 + lrow;
    float bv = b1[col];
#pragma unroll
    for (int mi = 0; mi < 4; ++mi) {
#pragma unroll
      for (int r = 0; r < 4; ++r) {
        int row = mi * 16 + kq * 4 + r;
        float v = acc[mi][ni][r] + bv;
        v = v > 0.f ? v : 0.f;
        int byte = (row * 1024 + col * 2) ^ ((row & 7) << 4);
        *(__bf16*)((char*)h1 + byte) = (__bf16)v;
      }
    }
  }
  __syncthreads();   // h1 complete; sA region dead -> reusable (h2_lds)

  // ---- GEMM2 (barrier-free): h2[64x256] = relu(h1 @ W2 + b2) -> LDS ----
  {
    f32x4 acc2[4][2] = {};
#pragma unroll 4
    for (int kkg = 0; kkg < 16; ++kkg) {
      bf16x8 a2[4];
#pragma unroll
      for (int mi = 0; mi < 4; ++mi) {
        int byte = ((mi * 16 + lrow) * 1024 + kkg * 64 + kq * 16) ^ ((lrow & 7) << 4);
        a2[mi] = *(const bf16x8*)((const char*)h1 + byte);
      }
#pragma unroll
      for (int ni = 0; ni < 2; ++ni) {
        bf16x8 bfr2 = *(const bf16x8*)(W2P +
            ((long)((w * 2 + ni) * 16 + kkg) * 64 + lane) * 8);
#pragma unroll
        for (int mi = 0; mi < 4; ++mi)
          acc2[mi][ni] = MFMA(a2[mi], bfr2, acc2[mi][ni]);
      }
    }
    // h2 -> LDS (rows 512B, swizzled by row&7)
#pragma unroll
    for (int ni = 0; ni < 2; ++ni) {
      int col = w * 32 + ni * 16 + lrow;
      float bv = b2[col];
#pragma unroll
      for (int mi = 0; mi < 4; ++mi) {
#pragma unroll
        for (int r = 0; r < 4; ++r) {
          int row = mi * 16 + kq * 4 + r;
          float v = acc2[mi][ni][r] + bv;
          v = v > 0.f ? v : 0.f;
          int byte = (row * 512 + col * 2) ^ ((row & 7) << 4);
          *(__bf16*)((char*)h2_lds + byte) = (__bf16)v;
        }
      }
    }
  }
  __syncthreads();   // h2 complete; h1 region dead -> t_lds

  // ---- Tower: wave w -> domain w>>1, rows (w&1)*32..+31, ONE pass ----
  {
    int d  = w >> 1;
    int r0 = (w & 1) * 32;
    __bf16* tw = t_lds + w * 4096;      // 8KB per wave (32 x 128 bf16)

    bf16x8 a1[2][8];
#pragma unroll
    for (int mi = 0; mi < 2; ++mi)
#pragma unroll
      for (int kk = 0; kk < 8; ++kk) {
        int row = r0 + mi * 16 + lrow;
        int byte = (row * 512 + (kk * 32 + kq * 8) * 2) ^ ((row & 7) << 4);
        a1[mi][kk] = *(const bf16x8*)((const char*)h2_lds + byte);
      }

    // t1 = relu(h2 @ TW1[d] + Tb1[d])  (32 x 128)
    f32x4 acc1[2][8] = {};
#pragma unroll
    for (int kk = 0; kk < 8; ++kk) {
#pragma unroll
      for (int ni = 0; ni < 8; ++ni) {
        bf16x8 b = *(const bf16x8*)(TW1P +
            ((long)(d * 64 + ni * 8 + kk) * 64 + lane) * 8);
#pragma unroll
        for (int mi = 0; mi < 2; ++mi)
          acc1[mi][ni] = MFMA(a1[mi][kk], b, acc1[mi][ni]);
      }
    }
#pragma unroll
    for (int ni = 0; ni < 8; ++ni) {
      float bv = Tb1[d * T1D + ni * 16 + lrow];
#pragma unroll
      for (int mi = 0; mi < 2; ++mi) {
#pragma unroll
        for (int r = 0; r < 4; ++r) {
          int lr = mi * 16 + kq * 4 + r;
          float v = acc1[mi][ni][r] + bv;
          v = v > 0.f ? v : 0.f;
          int byte = (lr * 256 + (ni * 16 + lrow) * 2) ^ ((lr & 7) << 4);
          *(__bf16*)((char*)tw + byte) = (__bf16)v;
        }
      }
    }
    asm volatile("s_waitcnt lgkmcnt(0)" ::: "memory");

    // t2 = relu(t1 @ TW2[d] + Tb2[d])  (32 x 64)
    bf16x8 a2f[2][4];
#pragma unroll
    for (int mi = 0; mi < 2; ++mi)
#pragma unroll
      for (int kk = 0; kk < 4; ++kk) {
        int lr = mi * 16 + lrow;
        int byte = (lr * 256 + (kk * 32 + kq * 8) * 2) ^ ((lr & 7) << 4);
        a2f[mi][kk] = *(const bf16x8*)((const char*)tw + byte);
      }
    asm volatile("s_waitcnt lgkmcnt(0)" ::: "memory");
    f32x4 acc2[2][4] = {};
#pragma unroll
    for (int kk = 0; kk < 4; ++kk) {
#pragma unroll
      for (int ni = 0; ni < 4; ++ni) {
        bf16x8 b = *(const bf16x8*)(TW2P +
            ((long)(d * 16 + ni * 4 + kk) * 64 + lane) * 8);
#pragma unroll
        for (int mi = 0; mi < 2; ++mi)
          acc2[mi][ni] = MFMA(a2f[mi][kk], b, acc2[mi][ni]);
      }
    }
#pragma unroll
    for (int ni = 0; ni < 4; ++ni) {
      float bv = Tb2[d * T2D + ni * 16 + lrow];
#pragma unroll
      for (int mi = 0; mi < 2; ++mi) {
#pragma unroll
        for (int r = 0; r < 4; ++r) {
          int lr = mi * 16 + kq * 4 + r;
          float v = acc2[mi][ni][r] + bv;
          v = v > 0.f ? v : 0.f;
          int byte = (lr * 128 + (ni * 16 + lrow) * 2) ^ ((lr & 7) << 4);
          *(__bf16*)((char*)tw + byte) = (__bf16)v;
        }
      }
    }
    asm volatile("s_waitcnt lgkmcnt(0)" ::: "memory");

    // logit + sigmoid + select-store
    {
      int lr    = (kq & 1) * 16 + lrow;
      int khalf = kq >> 1;
      float s = 0.f;
#pragma unroll
      for (int j = 0; j < 32; ++j) {
        int col = khalf * 32 + j;
        int byte = (lr * 128 + col * 2) ^ ((lr & 7) << 4);
        s += (float)*(const __bf16*)((const char*)tw + byte) * TW3[d * T2D + col];
      }
      s += __shfl_xor(s, 32);
      s += Tb3[d];
      int grow = r0 + lr;
      if (khalf == 0 && dom[m0 + grow] == d)
        out[m0 + grow] = 1.0f / (1.0f + expf(-s));
    }
  }
}

// ---------------------------------------------------------------------------
extern "C" void kernel_launch(void* const* d_in, const int* in_sizes, int n_in,
                              void* d_out, int out_size, void* d_ws, size_t ws_size,
                              hipStream_t stream) {
  const int*   fids = (const int*)d_in[0];
  const int*   dom  = (const int*)d_in[1];
  const float* emb  = (const float*)d_in[2];
  const float* W1   = (const float*)d_in[3];
  const float* b1   = (const float*)d_in[4];
  const float* W2   = (const float*)d_in[5];
  const float* b2   = (const float*)d_in[6];
  const float* TW1  = (const float*)d_in[7];
  const float* Tb1  = (const float*)d_in[8];
  const float* TW2  = (const float*)d_in[9];
  const float* Tb2  = (const float*)d_in[10];
  const float* TW3  = (const float*)d_in[11];
  const float* Tb3  = (const float*)d_in[12];
  float* out = (float*)d_out;

  char* ws = (char*)d_ws;
  __bf16* W1P   = (__bf16*)(ws);                 // 655360
  __bf16* W2P   = (__bf16*)(ws + 655360);        // 262144
  __bf16* TW1P  = (__bf16*)(ws + 917504);        // 262144
  __bf16* TW2P  = (__bf16*)(ws + 1179648);       // 65536

  k_prep<<<304, 256, 0, stream>>>(W1, W2, TW1, TW2, W1P, W2P, TW1P, TW2P);
  k_mega<<<256, 512, 0, stream>>>(fids, dom, emb, W1P, b1, W2P, b2,
                                  TW1P, TW2P, Tb1, Tb2, TW3, Tb3, out);
}